// Round 3
// baseline (437.788 us; speedup 1.0000x reference)
//
#include <hip/hip_runtime.h>
#include <hip/hip_bf16.h>

typedef __bf16  bf16x8 __attribute__((ext_vector_type(8)));
typedef float   f32x4  __attribute__((ext_vector_type(4)));

#define EMB   1024
#define HD    64
#define NH    16
#define SEQ   2048
#define BATCH 2
#define TOKENS (BATCH*SEQ)          // 4096 rows in all GEMMs

// 8-element loader: fp32 source converts to bf16; bf16 source is a raw 16B copy.
__device__ inline void load8(const float* p, __bf16* dst) {
    float4 a = *(const float4*)p;
    float4 b = *(const float4*)(p + 4);
    dst[0] = (__bf16)a.x; dst[1] = (__bf16)a.y; dst[2] = (__bf16)a.z; dst[3] = (__bf16)a.w;
    dst[4] = (__bf16)b.x; dst[5] = (__bf16)b.y; dst[6] = (__bf16)b.z; dst[7] = (__bf16)b.w;
}
__device__ inline void load8(const __bf16* p, __bf16* dst) {
    *(uint4*)dst = *(const uint4*)p;
}

// ---------------------------------------------------------------------------
// Y[M,N] = X[M,K] @ W[N,K]^T + bias[N]   (M=4096, N=K=1024), fp32 acc
// block = 256 thr (4 waves), tile 64x64, BK=32; wave -> 32x32 (2x2 MFMA 16x16x32)
// TY = output element type (bf16 for intermediates, float for d_out).
// ---------------------------------------------------------------------------
template <typename TX, typename TW, typename TY>
__global__ __launch_bounds__(256) void gemm_bias_kernel(
    const TX* __restrict__ X, const TW* __restrict__ W,
    const float* __restrict__ bias, TY* __restrict__ Y)
{
    // LDS stride 56 elems = 112 B: multiple of 16 B (aligned b128) and
    // 28*row mod 32 walks all eight 4-bank groups -> only 2-way (free).
    __shared__ __bf16 As[64][56];
    __shared__ __bf16 Bs[64][56];

    const int tid  = threadIdx.x;
    const int wave = tid >> 6;
    const int lane = tid & 63;
    const int quad = lane >> 4;
    const int l16  = lane & 15;
    const int warp_m = wave & 1;      // 2x2 wave grid over 64x64 tile
    const int warp_n = wave >> 1;

    const int bm = blockIdx.y;        // 64-row tile
    const int bn = blockIdx.x;        // 64-col tile

    // staging: thread -> (row 0..63, 8-elem col group 0..3)
    const int lrow = tid >> 2;
    const int lcol = (tid & 3) << 3;
    const TX* Xp = X + (size_t)(bm * 64 + lrow) * EMB + lcol;
    const TW* Wp = W + (size_t)(bn * 64 + lrow) * EMB + lcol;

    f32x4 acc[2][2] = {};

    for (int k0 = 0; k0 < EMB; k0 += 32) {
        __bf16 abuf[8], bbuf[8];
        load8(Xp + k0, abuf);
        load8(Wp + k0, bbuf);
        __syncthreads();                       // prev iter's readers done
        *(uint4*)&As[lrow][lcol] = *(const uint4*)abuf;
        *(uint4*)&Bs[lrow][lcol] = *(const uint4*)bbuf;
        __syncthreads();                       // staging visible

        bf16x8 a0 = *(const bf16x8*)&As[warp_m * 32 +      l16][quad * 8];
        bf16x8 a1 = *(const bf16x8*)&As[warp_m * 32 + 16 + l16][quad * 8];
        bf16x8 b0 = *(const bf16x8*)&Bs[warp_n * 32 +      l16][quad * 8];
        bf16x8 b1 = *(const bf16x8*)&Bs[warp_n * 32 + 16 + l16][quad * 8];

        acc[0][0] = __builtin_amdgcn_mfma_f32_16x16x32_bf16(a0, b0, acc[0][0], 0, 0, 0);
        acc[0][1] = __builtin_amdgcn_mfma_f32_16x16x32_bf16(a0, b1, acc[0][1], 0, 0, 0);
        acc[1][0] = __builtin_amdgcn_mfma_f32_16x16x32_bf16(a1, b0, acc[1][0], 0, 0, 0);
        acc[1][1] = __builtin_amdgcn_mfma_f32_16x16x32_bf16(a1, b1, acc[1][1], 0, 0, 0);
    }

    #pragma unroll
    for (int sm = 0; sm < 2; ++sm)
        #pragma unroll
        for (int sn = 0; sn < 2; ++sn)
            #pragma unroll
            for (int r = 0; r < 4; ++r) {
                int m = bm * 64 + warp_m * 32 + sm * 16 + quad * 4 + r;
                int n = bn * 64 + warp_n * 32 + sn * 16 + l16;
                float v = acc[sm][sn][r] + bias[n];
                Y[(size_t)m * EMB + n] = (TY)v;
            }
}

// ---------------------------------------------------------------------------
// Flash attention fwd: per block = 64 q rows x one (head, batch).
// 4 waves, each owns 16 q rows. K-tile = 32 keys/iter, online softmax.
// Qp/Kp/Vp/Op are [B, SEQ, EMB] bf16 with heads along EMB.
// ---------------------------------------------------------------------------
__global__ __launch_bounds__(256) void attn_kernel(
    const __bf16* __restrict__ Qp, const __bf16* __restrict__ Kp,
    const __bf16* __restrict__ Vp, __bf16* __restrict__ Op)
{
    __shared__ __bf16 Ks[32][72];        // [key][d]   144 B rows, aligned
    __shared__ __bf16 Vt[64][56];        // [d][key]   transposed at staging
    __shared__ __bf16 Plds[4][16][56];   // per-wave P transpose buffer

    const int tid  = threadIdx.x;
    const int wave = tid >> 6;
    const int lane = tid & 63;
    const int quad = lane >> 4;
    const int l16  = lane & 15;

    const int qt = blockIdx.x;           // 0..31
    const int h  = blockIdx.y;           // 0..15
    const int b  = blockIdx.z;           // 0..1

    const size_t base = (size_t)b * SEQ * EMB + (size_t)h * HD;
    const int qbase = qt * 64 + wave * 16;

    // Q fragments (A-layout), pinned for whole loop: d in [0,32) and [32,64)
    const __bf16* qrow = Qp + base + (size_t)(qbase + l16) * EMB;
    bf16x8 aq0 = *(const bf16x8*)(qrow +      quad * 8);
    bf16x8 aq1 = *(const bf16x8*)(qrow + 32 + quad * 8);

    float m_run[4], l_run[4];
    f32x4 oacc[4] = {};
    #pragma unroll
    for (int r = 0; r < 4; ++r) { m_run[r] = -1e30f; l_run[r] = 0.f; }

    const __bf16* Kb = Kp + base;
    const __bf16* Vb = Vp + base;

    // staging mapping: thread -> key row (0..31), 8-elem d group (0..7)
    const int srow = tid >> 3;
    const int scol = (tid & 7) << 3;

    for (int kb = 0; kb < SEQ; kb += 32) {
        uint4 kv = *(const uint4*)(Kb + (size_t)(kb + srow) * EMB + scol);
        uint4 vv = *(const uint4*)(Vb + (size_t)(kb + srow) * EMB + scol);
        __syncthreads();                      // prev iter's K/V readers done
        *(uint4*)&Ks[srow][scol] = kv;
        const __bf16* vp = (const __bf16*)&vv;
        #pragma unroll
        for (int j = 0; j < 8; ++j) Vt[scol + j][srow] = vp[j];
        __syncthreads();                      // staging visible

        // S = Q K^T  (two 16-key halves x two 32-d steps)
        f32x4 s0 = {}, s1 = {};
        bf16x8 k0a = *(const bf16x8*)&Ks[     l16][     quad * 8];
        bf16x8 k0b = *(const bf16x8*)&Ks[     l16][32 + quad * 8];
        bf16x8 k1a = *(const bf16x8*)&Ks[16 + l16][     quad * 8];
        bf16x8 k1b = *(const bf16x8*)&Ks[16 + l16][32 + quad * 8];
        s0 = __builtin_amdgcn_mfma_f32_16x16x32_bf16(aq0, k0a, s0, 0, 0, 0);
        s0 = __builtin_amdgcn_mfma_f32_16x16x32_bf16(aq1, k0b, s0, 0, 0, 0);
        s1 = __builtin_amdgcn_mfma_f32_16x16x32_bf16(aq0, k1a, s1, 0, 0, 0);
        s1 = __builtin_amdgcn_mfma_f32_16x16x32_bf16(aq1, k1b, s1, 0, 0, 0);

        // scale + online softmax (row r lives across the 16 lanes of a quad)
        float mt[4], alpha[4], psum[4];
        #pragma unroll
        for (int r = 0; r < 4; ++r) {
            s0[r] *= 0.125f; s1[r] *= 0.125f;
            mt[r] = fmaxf(s0[r], s1[r]);
        }
        #pragma unroll
        for (int off = 1; off < 16; off <<= 1)
            #pragma unroll
            for (int r = 0; r < 4; ++r)
                mt[r] = fmaxf(mt[r], __shfl_xor(mt[r], off, 64));
        #pragma unroll
        for (int r = 0; r < 4; ++r) {
            float mn = fmaxf(m_run[r], mt[r]);
            alpha[r] = __expf(m_run[r] - mn);
            m_run[r] = mn;
            s0[r] = __expf(s0[r] - mn);
            s1[r] = __expf(s1[r] - mn);
            psum[r] = s0[r] + s1[r];
        }
        #pragma unroll
        for (int off = 1; off < 16; off <<= 1)
            #pragma unroll
            for (int r = 0; r < 4; ++r)
                psum[r] += __shfl_xor(psum[r], off, 64);
        #pragma unroll
        for (int r = 0; r < 4; ++r)
            l_run[r] = l_run[r] * alpha[r] + psum[r];
        #pragma unroll
        for (int dt = 0; dt < 4; ++dt)
            #pragma unroll
            for (int r = 0; r < 4; ++r)
                oacc[dt][r] *= alpha[r];

        // P: C-layout -> LDS -> A-layout
        #pragma unroll
        for (int r = 0; r < 4; ++r) {
            int q = quad * 4 + r;
            Plds[wave][q][     l16] = (__bf16)s0[r];
            Plds[wave][q][16 + l16] = (__bf16)s1[r];
        }
        __syncthreads();                      // P visible for frag reads

        bf16x8 ap = *(const bf16x8*)&Plds[wave][l16][quad * 8];
        #pragma unroll
        for (int dt = 0; dt < 4; ++dt) {
            bf16x8 bvf = *(const bf16x8*)&Vt[dt * 16 + l16][quad * 8];
            oacc[dt] = __builtin_amdgcn_mfma_f32_16x16x32_bf16(ap, bvf, oacc[dt], 0, 0, 0);
        }
    }

    #pragma unroll
    for (int dt = 0; dt < 4; ++dt)
        #pragma unroll
        for (int r = 0; r < 4; ++r) {
            int q = qbase + quad * 4 + r;
            float v = oacc[dt][r] / l_run[r];
            Op[base + (size_t)q * EMB + dt * 16 + l16] = (__bf16)v;
        }
}

// ---------------------------------------------------------------------------
extern "C" void kernel_launch(void* const* d_in, const int* in_sizes, int n_in,
                              void* d_out, int out_size, void* d_ws, size_t ws_size,
                              hipStream_t stream) {
    const float* Qin = (const float*)d_in[0];
    const float* Kin = (const float*)d_in[1];
    const float* Vin = (const float*)d_in[2];
    const float* Wq  = (const float*)d_in[3];
    const float* bq  = (const float*)d_in[4];
    const float* Wk  = (const float*)d_in[5];
    const float* bk  = (const float*)d_in[6];
    const float* Wv  = (const float*)d_in[7];
    const float* bv  = (const float*)d_in[8];
    const float* Wo  = (const float*)d_in[9];
    const float* bo  = (const float*)d_in[10];

    const size_t TENS = (size_t)TOKENS * EMB;    // 4,194,304 elems
    __bf16* ws = (__bf16*)d_ws;
    __bf16* Qp = ws;
    __bf16* Kp = ws + TENS;
    __bf16* Vp = ws + 2 * TENS;
    __bf16* Ap = ws + 3 * TENS;

    dim3 gg(EMB / 64, TOKENS / 64);              // (16, 64)
    gemm_bias_kernel<float, float, __bf16><<<gg, 256, 0, stream>>>(Qin, Wq, bq, Qp);
    gemm_bias_kernel<float, float, __bf16><<<gg, 256, 0, stream>>>(Kin, Wk, bk, Kp);
    gemm_bias_kernel<float, float, __bf16><<<gg, 256, 0, stream>>>(Vin, Wv, bv, Vp);

    attn_kernel<<<dim3(SEQ / 64, NH, BATCH), 256, 0, stream>>>(Qp, Kp, Vp, Ap);

    // Final projection writes fp32 directly to d_out (reference output dtype).
    gemm_bias_kernel<__bf16, float, float><<<gg, 256, 0, stream>>>(Ap, Wo, bo, (float*)d_out);
}

// Round 6
// 373.380 us; speedup vs baseline: 1.1725x; 1.1725x over previous
//
#include <hip/hip_runtime.h>
#include <hip/hip_bf16.h>

typedef __bf16  bf16x8 __attribute__((ext_vector_type(8)));
typedef float   f32x4  __attribute__((ext_vector_type(4)));

#define EMB   1024
#define HD    64
#define NH    16
#define SEQ   2048
#define BATCH 2
#define TOKENS (BATCH*SEQ)          // 4096 rows in all GEMMs
#define TK    64                    // attention K-tile

// 8-element loader: fp32 source converts to bf16; bf16 source is a raw 16B copy.
__device__ inline void load8(const float* p, __bf16* dst) {
    float4 a = *(const float4*)p;
    float4 b = *(const float4*)(p + 4);
    dst[0] = (__bf16)a.x; dst[1] = (__bf16)a.y; dst[2] = (__bf16)a.z; dst[3] = (__bf16)a.w;
    dst[4] = (__bf16)b.x; dst[5] = (__bf16)b.y; dst[6] = (__bf16)b.z; dst[7] = (__bf16)b.w;
}
__device__ inline void load8(const __bf16* p, __bf16* dst) {
    *(uint4*)dst = *(const uint4*)p;
}

// ---------------------------------------------------------------------------
// Y[M,N] = X[M,K] @ W[N,K]^T + bias[N]  (M=4096, N=K=1024), fp32 acc
// block = 256 thr (4 waves), tile 64x64, BK=32; wave -> 32x32 (2x2 MFMA 16x16x32)
// R3-proven version: fp32 inputs converted in the staging path.
// ---------------------------------------------------------------------------
template <typename TX, typename TW, typename TY>
__global__ __launch_bounds__(256) void gemm_bias_kernel(
    const TX* __restrict__ X, const TW* __restrict__ W,
    const float* __restrict__ bias, TY* __restrict__ Y)
{
    __shared__ __bf16 As[64][56];   // stride 56: 112 B rows, b128-aligned, 2-way max
    __shared__ __bf16 Bs[64][56];

    const int tid  = threadIdx.x;
    const int wave = tid >> 6;
    const int lane = tid & 63;
    const int quad = lane >> 4;
    const int l16  = lane & 15;
    const int warp_m = wave & 1;
    const int warp_n = wave >> 1;

    const int bm = blockIdx.y;
    const int bn = blockIdx.x;

    const int lrow = tid >> 2;
    const int lcol = (tid & 3) << 3;
    const TX* Xp = X + (size_t)(bm * 64 + lrow) * EMB + lcol;
    const TW* Wp = W + (size_t)(bn * 64 + lrow) * EMB + lcol;

    f32x4 acc[2][2] = {};

    for (int k0 = 0; k0 < EMB; k0 += 32) {
        __bf16 abuf[8], bbuf[8];
        load8(Xp + k0, abuf);
        load8(Wp + k0, bbuf);
        __syncthreads();
        *(uint4*)&As[lrow][lcol] = *(const uint4*)abuf;
        *(uint4*)&Bs[lrow][lcol] = *(const uint4*)bbuf;
        __syncthreads();

        bf16x8 a0 = *(const bf16x8*)&As[warp_m * 32 +      l16][quad * 8];
        bf16x8 a1 = *(const bf16x8*)&As[warp_m * 32 + 16 + l16][quad * 8];
        bf16x8 b0 = *(const bf16x8*)&Bs[warp_n * 32 +      l16][quad * 8];
        bf16x8 b1 = *(const bf16x8*)&Bs[warp_n * 32 + 16 + l16][quad * 8];

        acc[0][0] = __builtin_amdgcn_mfma_f32_16x16x32_bf16(a0, b0, acc[0][0], 0, 0, 0);
        acc[0][1] = __builtin_amdgcn_mfma_f32_16x16x32_bf16(a0, b1, acc[0][1], 0, 0, 0);
        acc[1][0] = __builtin_amdgcn_mfma_f32_16x16x32_bf16(a1, b0, acc[1][0], 0, 0, 0);
        acc[1][1] = __builtin_amdgcn_mfma_f32_16x16x32_bf16(a1, b1, acc[1][1], 0, 0, 0);
    }

    #pragma unroll
    for (int sm = 0; sm < 2; ++sm)
        #pragma unroll
        for (int sn = 0; sn < 2; ++sn)
            #pragma unroll
            for (int r = 0; r < 4; ++r) {
                int m = bm * 64 + warp_m * 32 + sm * 16 + quad * 4 + r;
                int n = bn * 64 + warp_n * 32 + sn * 16 + l16;
                float v = acc[sm][sn][r] + bias[n];
                Y[(size_t)m * EMB + n] = (TY)v;
            }
}

// ---------------------------------------------------------------------------
// Flash attention: block = 64 q rows x (head, batch); 4 waves x 16 q rows.
// K-tile = 64 keys, double-buffered LDS, XOR-swizzled V^T, wave-local P sync.
// ---------------------------------------------------------------------------
__global__ __launch_bounds__(256) void attn_kernel(
    const __bf16* __restrict__ Qp, const __bf16* __restrict__ Kp,
    const __bf16* __restrict__ Vp, __bf16* __restrict__ Op)
{
    // Ks rows hold HD=64 d-elements -> stride MUST be >= 64. (R4/R5 bug: 40.)
    __shared__ __bf16 Ks[2][64][72];     // [buf][key][d]          144 B rows
    __shared__ __bf16 Vt[2][64][72];     // [buf][d][key-swizzled] 144 B rows
    __shared__ __bf16 Plds[4][16][72];   // per-wave P transpose buffer

    const int tid  = threadIdx.x;
    const int wave = tid >> 6;
    const int lane = tid & 63;
    const int quad = lane >> 4;
    const int l16  = lane & 15;

    const int qt = blockIdx.x;
    const int h  = blockIdx.y;
    const int b  = blockIdx.z;

    const size_t base = (size_t)b * SEQ * EMB + (size_t)h * HD;
    const int qbase = qt * 64 + wave * 16;

    // Q fragments (A-layout), pre-scaled by 1/sqrt(64) (exact in bf16)
    const __bf16* qrow = Qp + base + (size_t)(qbase + l16) * EMB;
    bf16x8 aq0 = *(const bf16x8*)(qrow +      quad * 8);
    bf16x8 aq1 = *(const bf16x8*)(qrow + 32 + quad * 8);
    #pragma unroll
    for (int i = 0; i < 8; ++i) {
        aq0[i] = (__bf16)((float)aq0[i] * 0.125f);
        aq1[i] = (__bf16)((float)aq1[i] * 0.125f);
    }

    float m_run[4], l_run[4];
    f32x4 oacc[4] = {};
    #pragma unroll
    for (int r = 0; r < 4; ++r) { m_run[r] = -1e30f; l_run[r] = 0.f; }

    const __bf16* Kg = Kp + base;
    const __bf16* Vg = Vp + base;

    // staging: thread -> key rows (srow, srow+32), 8-elem d group
    const int srow = tid >> 3;           // 0..31
    const int scol = (tid & 7) << 3;     // 0..56
    const int g0 = srow >> 3;            // key group 0..3
    const int g1 = g0 + 4;               // key group for srow+32

    // ---- prologue: stage tile 0 into buf 0 ----
    {
        uint4 k0 = *(const uint4*)(Kg + (size_t)(srow     ) * EMB + scol);
        uint4 k1 = *(const uint4*)(Kg + (size_t)(srow + 32) * EMB + scol);
        uint4 v0 = *(const uint4*)(Vg + (size_t)(srow     ) * EMB + scol);
        uint4 v1 = *(const uint4*)(Vg + (size_t)(srow + 32) * EMB + scol);
        *(uint4*)&Ks[0][srow     ][scol] = k0;
        *(uint4*)&Ks[0][srow + 32][scol] = k1;
        const __bf16* p0 = (const __bf16*)&v0;
        const __bf16* p1 = (const __bf16*)&v1;
        #pragma unroll
        for (int j = 0; j < 8; ++j) {
            int d  = scol + j;
            int gg = (d >> 3) & 7;
            Vt[0][d][((g0 ^ gg) << 3) + (srow & 7)] = p0[j];
            Vt[0][d][((g1 ^ gg) << 3) + (srow & 7)] = p1[j];
        }
    }
    __syncthreads();

    for (int t = 0; t < SEQ / TK; ++t) {
        const int cur = t & 1, nxt = cur ^ 1;
        const bool have_next = (t + 1) < SEQ / TK;
        uint4 nk0, nk1, nv0, nv1;
        if (have_next) {
            int kb = (t + 1) * TK;
            nk0 = *(const uint4*)(Kg + (size_t)(kb + srow     ) * EMB + scol);
            nk1 = *(const uint4*)(Kg + (size_t)(kb + srow + 32) * EMB + scol);
            nv0 = *(const uint4*)(Vg + (size_t)(kb + srow     ) * EMB + scol);
            nv1 = *(const uint4*)(Vg + (size_t)(kb + srow + 32) * EMB + scol);
        }

        // ---- S = Q K^T over 64 keys ----
        f32x4 s[4] = {};
        #pragma unroll
        for (int kb16 = 0; kb16 < 4; ++kb16) {
            bf16x8 klo = *(const bf16x8*)&Ks[cur][kb16 * 16 + l16][     quad * 8];
            bf16x8 khi = *(const bf16x8*)&Ks[cur][kb16 * 16 + l16][32 + quad * 8];
            s[kb16] = __builtin_amdgcn_mfma_f32_16x16x32_bf16(aq0, klo, s[kb16], 0, 0, 0);
            s[kb16] = __builtin_amdgcn_mfma_f32_16x16x32_bf16(aq1, khi, s[kb16], 0, 0, 0);
        }

        // ---- online softmax (row r spans the 16 lanes of a quad) ----
        float mt[4], alpha[4], psum[4];
        #pragma unroll
        for (int r = 0; r < 4; ++r)
            mt[r] = fmaxf(fmaxf(s[0][r], s[1][r]), fmaxf(s[2][r], s[3][r]));
        #pragma unroll
        for (int off = 1; off < 16; off <<= 1)
            #pragma unroll
            for (int r = 0; r < 4; ++r)
                mt[r] = fmaxf(mt[r], __shfl_xor(mt[r], off, 64));
        #pragma unroll
        for (int r = 0; r < 4; ++r) {
            float mn = fmaxf(m_run[r], mt[r]);
            alpha[r] = __expf(m_run[r] - mn);
            m_run[r] = mn;
            psum[r] = 0.f;
            #pragma unroll
            for (int kb16 = 0; kb16 < 4; ++kb16) {
                s[kb16][r] = __expf(s[kb16][r] - mn);
                psum[r] += s[kb16][r];
            }
        }
        #pragma unroll
        for (int off = 1; off < 16; off <<= 1)
            #pragma unroll
            for (int r = 0; r < 4; ++r)
                psum[r] += __shfl_xor(psum[r], off, 64);
        #pragma unroll
        for (int r = 0; r < 4; ++r)
            l_run[r] = l_run[r] * alpha[r] + psum[r];
        #pragma unroll
        for (int dt = 0; dt < 4; ++dt)
            #pragma unroll
            for (int r = 0; r < 4; ++r)
                oacc[dt][r] *= alpha[r];

        // ---- P: C-layout -> wave-private LDS -> A-layout ----
        #pragma unroll
        for (int kb16 = 0; kb16 < 4; ++kb16)
            #pragma unroll
            for (int r = 0; r < 4; ++r)
                Plds[wave][quad * 4 + r][kb16 * 16 + l16] = (__bf16)s[kb16][r];
        // wave-local: DS ops from one wave return in order; fence stops compiler reorder
        __builtin_amdgcn_fence(__ATOMIC_ACQ_REL, "workgroup");

        bf16x8 ap0 = *(const bf16x8*)&Plds[wave][l16][     quad * 8];
        bf16x8 ap1 = *(const bf16x8*)&Plds[wave][l16][32 + quad * 8];
        #pragma unroll
        for (int dt = 0; dt < 4; ++dt) {
            int d  = dt * 16 + l16;
            int gg = (d >> 3) & 7;
            bf16x8 bv0 = *(const bf16x8*)&Vt[cur][d][(( quad     ^ gg) << 3)];
            bf16x8 bv1 = *(const bf16x8*)&Vt[cur][d][(((quad + 4) ^ gg) << 3)];
            oacc[dt] = __builtin_amdgcn_mfma_f32_16x16x32_bf16(ap0, bv0, oacc[dt], 0, 0, 0);
            oacc[dt] = __builtin_amdgcn_mfma_f32_16x16x32_bf16(ap1, bv1, oacc[dt], 0, 0, 0);
        }

        // ---- stage tile t+1 into the other buffer ----
        if (have_next) {
            *(uint4*)&Ks[nxt][srow     ][scol] = nk0;
            *(uint4*)&Ks[nxt][srow + 32][scol] = nk1;
            const __bf16* p0 = (const __bf16*)&nv0;
            const __bf16* p1 = (const __bf16*)&nv1;
            #pragma unroll
            for (int j = 0; j < 8; ++j) {
                int d  = scol + j;
                int gg = (d >> 3) & 7;
                Vt[nxt][d][((g0 ^ gg) << 3) + (srow & 7)] = p0[j];
                Vt[nxt][d][((g1 ^ gg) << 3) + (srow & 7)] = p1[j];
            }
        }
        __syncthreads();   // readers of cur done + nxt staged, for everyone
    }

    #pragma unroll
    for (int dt = 0; dt < 4; ++dt)
        #pragma unroll
        for (int r = 0; r < 4; ++r) {
            int q = qbase + quad * 4 + r;
            float v = oacc[dt][r] / l_run[r];
            Op[base + (size_t)q * EMB + dt * 16 + l16] = (__bf16)v;
        }
}

// ---------------------------------------------------------------------------
extern "C" void kernel_launch(void* const* d_in, const int* in_sizes, int n_in,
                              void* d_out, int out_size, void* d_ws, size_t ws_size,
                              hipStream_t stream) {
    const float* Qin = (const float*)d_in[0];
    const float* Kin = (const float*)d_in[1];
    const float* Vin = (const float*)d_in[2];
    const float* Wq  = (const float*)d_in[3];
    const float* bq  = (const float*)d_in[4];
    const float* Wk  = (const float*)d_in[5];
    const float* bk  = (const float*)d_in[6];
    const float* Wv  = (const float*)d_in[7];
    const float* bv  = (const float*)d_in[8];
    const float* Wo  = (const float*)d_in[9];
    const float* bo  = (const float*)d_in[10];

    // ws footprint: exactly 4*TENS*2B = 32 MiB (R3-proven)
    const size_t TENS = (size_t)TOKENS * EMB;    // 4,194,304 elems
    __bf16* ws = (__bf16*)d_ws;
    __bf16* Qp = ws;
    __bf16* Kp = ws + TENS;
    __bf16* Vp = ws + 2 * TENS;
    __bf16* Ap = ws + 3 * TENS;

    dim3 gg(EMB / 64, TOKENS / 64);              // (16, 64)
    gemm_bias_kernel<float, float, __bf16><<<gg, 256, 0, stream>>>(Qin, Wq, bq, Qp);
    gemm_bias_kernel<float, float, __bf16><<<gg, 256, 0, stream>>>(Kin, Wk, bk, Kp);
    gemm_bias_kernel<float, float, __bf16><<<gg, 256, 0, stream>>>(Vin, Wv, bv, Vp);

    attn_kernel<<<dim3(SEQ / 64, NH, BATCH), 256, 0, stream>>>(Qp, Kp, Vp, Ap);

    gemm_bias_kernel<__bf16, float, float><<<gg, 256, 0, stream>>>(Ap, Wo, bo, (float*)d_out);
}